// Round 1
// baseline (732.710 us; speedup 1.0000x reference)
//
#include <hip/hip_runtime.h>

// RoIAlign (legacy/caffe-style, aligned=False variant per reference):
//   features: (B=4, C=1024, H=64, W=64) fp32
//   rois:     (N=2048, 5) fp32  [batch, x1, y1, x2, y2] in image coords
//   out:      (N, C, 7, 7) fp32
//
// Strategy: per-bin bilinear params (4 corner weights + base offset) are
// computed once per block into LDS (they depend only on the roi+bin, not the
// channel); then the block streams 256 channels x 49 bins with perfectly
// coalesced nontemporal stores and 4 scattered cached gathers per element.

#define SCALE    0.0625f
#define C_       1024
#define H_       64
#define W_       64
#define AH_      7
#define AW_      7
#define NBIN     49            // 7*7
#define PER_ROI  (C_ * NBIN)   // 50176
#define QCH      256           // channels handled per block
#define QELEM    (QCH * NBIN)  // 12544

__global__ __launch_bounds__(256, 8) void roialign_kernel(
    const float* __restrict__ feat,
    const float* __restrict__ rois,
    float* __restrict__ out)
{
    __shared__ float4 s_w[NBIN];   // corner weights (ul, ur, dl, dr)
    __shared__ int    s_off[NBIN]; // base offset: b*C*H*W + hs*W + ws

    const int n = blockIdx.x >> 2;   // roi index
    const int q = blockIdx.x & 3;    // channel-quarter index
    const int t = threadIdx.x;

    if (t < NBIN) {
        // Match numpy rounding exactly: no FMA contraction here, so floor()
        // boundary decisions agree with the reference bit-for-bit.
        #pragma clang fp contract(off)
        const float r0 = rois[n * 5 + 0];
        const float r1 = rois[n * 5 + 1];
        const float r2 = rois[n * 5 + 2];
        const float r3 = rois[n * 5 + 3];
        const float r4 = rois[n * 5 + 4];
        const int   b  = (int)r0;
        const float x1 = r1 * SCALE;
        const float y1 = r2 * SCALE;
        const float x2 = r3 * SCALE;
        const float y2 = r4 * SCALE;
        const float roi_w = fmaxf(x2 - x1, 0.0f);
        const float roi_h = fmaxf(y2 - y1, 0.0f);
        const float bin_w = roi_w / (float)(AW_ - 1);  // IEEE divide
        const float bin_h = roi_h / (float)(AH_ - 1);

        const int ph = t / AW_;
        const int pw = t - ph * AW_;

        const float h = y1 + (float)ph * bin_h;
        const float w = x1 + (float)pw * bin_w;

        const float hstart = fminf(floorf(h), (float)(H_ - 2));
        const float wstart = fminf(floorf(w), (float)(W_ - 2));
        const float hr = h - hstart;
        const float wr = w - wstart;

        const bool valid = (h >= 0.0f) && (h < (float)H_) &&
                           (w >= 0.0f) && (w < (float)W_);

        const int hs = min(max((int)hstart, 0), H_ - 2);
        const int ws = min(max((int)wstart, 0), W_ - 2);

        float wul = (1.0f - hr) * (1.0f - wr);
        float wur = (1.0f - hr) * wr;
        float wdl = hr * (1.0f - wr);
        float wdr = hr * wr;
        if (!valid) { wul = 0.0f; wur = 0.0f; wdl = 0.0f; wdr = 0.0f; }

        s_w[t]   = make_float4(wul, wur, wdl, wdr);
        s_off[t] = b * (C_ * H_ * W_) + hs * W_ + ws;
    }
    __syncthreads();

    float* ob = out + (size_t)n * PER_ROI;
    const int e_end = (q + 1) * QELEM;
    for (int e = q * QELEM + t; e < e_end; e += 256) {
        const unsigned eu  = (unsigned)e;
        const unsigned c   = eu / NBIN;        // magic-mul division
        const unsigned bin = eu - c * NBIN;

        const float4 wg  = s_w[bin];
        const int    off = s_off[bin] + (int)(c << 12);  // c * H*W (4096)

        const float ul = feat[off];
        const float ur = feat[off + 1];
        const float dl = feat[off + W_];
        const float dr = feat[off + W_ + 1];

        const float v = ul * wg.x + ur * wg.y + dl * wg.z + dr * wg.w;
        __builtin_nontemporal_store(v, ob + e);
    }
}

extern "C" void kernel_launch(void* const* d_in, const int* in_sizes, int n_in,
                              void* d_out, int out_size, void* d_ws, size_t ws_size,
                              hipStream_t stream) {
    const float* feat = (const float*)d_in[0];
    const float* rois = (const float*)d_in[1];
    float* out = (float*)d_out;
    const int N = in_sizes[1] / 5;  // 2048
    dim3 grid(N * 4);
    dim3 block(256);
    roialign_kernel<<<grid, block, 0, stream>>>(feat, rois, out);
}